// Round 5
// baseline (467.192 us; speedup 1.0000x reference)
//
#include <hip/hip_runtime.h>
#include <hip/hip_bf16.h>

// B=8, T=2048, D=1024, E=1024
//   k0: WT = bf16(W^T)                  -> d_out[32MiB..34MiB] (dead before k4)
//   k1: y = bf16(x@W + b)               -> d_out[0:32MiB]   (MFMA, pk-cvt A)
//   k2: S[b,t,s] = bf16(y_t.y_s/32)     -> d_ws, lower-triangle tiles (BK=64)
//   k2b: col stats m_s,r_s=1/z_s        -> stashed in S's dead zone
//   k3: P = exp(S-m_s)*r_s in place     (causal-restricted)
//   k4: out = P @ x  fp32               (MFMA, B via LDS fp32 transpose stage)
//
// MFMA 16x16x32 bf16 frag layouts (HW-verified):
//   A: lane holds A[m=lane&15][k=q*8+j]; B: B[k=q*8+j][n=lane&15]
//   C/D: lane,reg r -> D[row=q*4+r][col=lane&15]
// LDS pitches: PIT=56 shorts (112B=7*16) for 32-wide k rows; PIT2=72 shorts
// (144B=9*16) for 64-wide k rows. Both: frag b128 reads land 2-way/bank = free.

#define B_ 8
#define T_ 2048
#define D_ 1024
#define E_ 1024
#define PIT 56
#define PIT2 72

typedef unsigned short u16;
typedef __attribute__((ext_vector_type(8))) short short8;
typedef __attribute__((ext_vector_type(4))) float floatx4;

__device__ __forceinline__ float b2f(u16 u) {
    unsigned v = ((unsigned)u) << 16;
    float f; __builtin_memcpy(&f, &v, 4); return f;
}
__device__ __forceinline__ u16 f2b(float f) {
    unsigned v; __builtin_memcpy(&v, &f, 4);
    v = (v + 0x7FFFu + ((v >> 16) & 1u)) >> 16;   // RNE
    return (u16)v;
}
// packed 2xfp32 -> 2xbf16 (v_cvt_pk_bf16_f32 on gfx950)
__device__ __forceinline__ unsigned pkbf(float a, float b) {
    __hip_bfloat162 h = __float22bfloat162_rn(make_float2(a, b));
    unsigned u; __builtin_memcpy(&u, &h, 4); return u;
}

// m/r stash inside S's strictly-upper dead zone (batch 0, rows 0..63, cols 1024+).
__device__ __forceinline__ float* mr_ptr(u16* S, int which, int b, int s) {
    const int row = which * 32 + b * 4 + (s >> 9);
    return (float*)(S + (size_t)row * T_ + 1024 + (s & 511) * 2);
}

// ---------------- K0: WT[n][k] = bf16(W[k][n]) ----------------
__global__ __launch_bounds__(256) void k0_wt(const float* __restrict__ W,
                                             u16* __restrict__ WT)
{
    __shared__ float Ws[64 * 68];
    const int tid = threadIdx.x;
    const int k0 = blockIdx.x * 64, n0 = blockIdx.y * 64;
#pragma unroll
    for (int u = 0; u < 4; u++) {
        const int c = tid + 256 * u;
        const int row = c >> 4, c4 = c & 15;
        float4 v = *(const float4*)(W + (size_t)(k0 + row) * E_ + n0 + c4 * 4);
        *(float4*)&Ws[row * 68 + c4 * 4] = v;
    }
    __syncthreads();
#pragma unroll
    for (int u = 0; u < 2; u++) {
        const int c = tid + 256 * u;
        const int n = c >> 3, kc = c & 7;
        unsigned pk[4];
#pragma unroll
        for (int j = 0; j < 4; j++)
            pk[j] = pkbf(Ws[(kc * 8 + 2 * j) * 68 + n], Ws[(kc * 8 + 2 * j + 1) * 68 + n]);
        *(uint4*)(WT + (size_t)(n0 + n) * D_ + k0 + kc * 8) = make_uint4(pk[0], pk[1], pk[2], pk[3]);
    }
}

// ---------------- K1: y = bf16(x @ W + b), MFMA ----------------
__global__ __launch_bounds__(256) void k1_proj(const float* __restrict__ x,
                                               const u16* __restrict__ WT,
                                               const float* __restrict__ bias,
                                               u16* __restrict__ y)
{
    __shared__ u16 As[128 * PIT];
    __shared__ u16 Bs[128 * PIT];
    const int tid = threadIdx.x;
    const int lane = tid & 63, wid = tid >> 6;
    const int wr = (wid >> 1) * 64, wc = (wid & 1) * 64;
    const int l15 = lane & 15, q = lane >> 4;
    const int m0 = blockIdx.y * 128, n0 = blockIdx.x * 128;

    floatx4 acc[4][4];
#pragma unroll
    for (int i = 0; i < 4; i++)
#pragma unroll
        for (int j = 0; j < 4; j++) acc[i][j] = (floatx4){0.f, 0.f, 0.f, 0.f};

    for (int k0 = 0; k0 < D_; k0 += 32) {
        __syncthreads();
#pragma unroll
        for (int u = 0; u < 4; u++) {
            const int c = tid * 4 + u;
            const int row = c >> 3, c4 = c & 7;
            float4 v = *(const float4*)(x + (size_t)(m0 + row) * D_ + k0 + c4 * 4);
            *(uint2*)&As[row * PIT + c4 * 4] = make_uint2(pkbf(v.x, v.y), pkbf(v.z, v.w));
        }
#pragma unroll
        for (int u = 0; u < 2; u++) {
            const int c = tid * 2 + u;
            const int row = c >> 2, off = c & 3;
            *(uint4*)&Bs[row * PIT + off * 8] =
                *(const uint4*)(WT + (size_t)(n0 + row) * D_ + k0 + off * 8);
        }
        __syncthreads();
        short8 a[4], b2[4];
#pragma unroll
        for (int i = 0; i < 4; i++) a[i] = *(const short8*)&As[(wr + i * 16 + l15) * PIT + q * 8];
#pragma unroll
        for (int j = 0; j < 4; j++) b2[j] = *(const short8*)&Bs[(wc + j * 16 + l15) * PIT + q * 8];
#pragma unroll
        for (int i = 0; i < 4; i++)
#pragma unroll
            for (int j = 0; j < 4; j++)
                acc[i][j] = __builtin_amdgcn_mfma_f32_16x16x32_bf16(a[i], b2[j], acc[i][j], 0, 0, 0);
    }
    float bv[4];
#pragma unroll
    for (int j = 0; j < 4; j++) bv[j] = bias[n0 + wc + j * 16 + l15];
#pragma unroll
    for (int i = 0; i < 4; i++)
#pragma unroll
        for (int j = 0; j < 4; j++)
#pragma unroll
            for (int r = 0; r < 4; r++) {
                const int gm = m0 + wr + i * 16 + q * 4 + r;
                const int gn = n0 + wc + j * 16 + l15;
                y[(size_t)gm * E_ + gn] = f2b(acc[i][j][r] + bv[j]);
            }
}

// ---------------- K2: S tiles = bf16(y_t . y_s / 32), lower triangle, BK=64 ----------------
__global__ __launch_bounds__(256) void k2_score(const u16* __restrict__ y,
                                                u16* __restrict__ S)
{
    __shared__ u16 As[128 * PIT2];
    __shared__ u16 Bs[128 * PIT2];
    const int tid = threadIdx.x;
    const int lane = tid & 63, wid = tid >> 6;
    const int wr = (wid >> 1) * 64, wc = (wid & 1) * 64;
    const int l15 = lane & 15, q = lane >> 4;
    int idx = blockIdx.x, it = 0, base = 0;
    while (base + it + 1 <= idx) { base += it + 1; it++; }
    const int js = idx - base;
    const int t0 = it * 128, s0 = js * 128;
    const int b = blockIdx.y;
    const u16* yb = y + (size_t)b * T_ * E_;

    floatx4 acc[4][4];
#pragma unroll
    for (int i = 0; i < 4; i++)
#pragma unroll
        for (int j = 0; j < 4; j++) acc[i][j] = (floatx4){0.f, 0.f, 0.f, 0.f};

    for (int k0 = 0; k0 < E_; k0 += 64) {
        __syncthreads();
#pragma unroll
        for (int u = 0; u < 4; u++) {            // A: 128 rows x 64 shorts
            const int c = tid + 256 * u;
            const int row = c >> 3, off = c & 7;
            *(uint4*)&As[row * PIT2 + off * 8] =
                *(const uint4*)(yb + (size_t)(t0 + row) * E_ + k0 + off * 8);
        }
#pragma unroll
        for (int u = 0; u < 4; u++) {
            const int c = tid + 256 * u;
            const int row = c >> 3, off = c & 7;
            *(uint4*)&Bs[row * PIT2 + off * 8] =
                *(const uint4*)(yb + (size_t)(s0 + row) * E_ + k0 + off * 8);
        }
        __syncthreads();
#pragma unroll
        for (int h = 0; h < 2; h++) {
            short8 a[4], b2[4];
#pragma unroll
            for (int i = 0; i < 4; i++)
                a[i] = *(const short8*)&As[(wr + i * 16 + l15) * PIT2 + h * 32 + q * 8];
#pragma unroll
            for (int j = 0; j < 4; j++)
                b2[j] = *(const short8*)&Bs[(wc + j * 16 + l15) * PIT2 + h * 32 + q * 8];
#pragma unroll
            for (int i = 0; i < 4; i++)
#pragma unroll
                for (int j = 0; j < 4; j++)
                    acc[i][j] = __builtin_amdgcn_mfma_f32_16x16x32_bf16(a[i], b2[j], acc[i][j], 0, 0, 0);
        }
    }
#pragma unroll
    for (int i = 0; i < 4; i++)
#pragma unroll
        for (int j = 0; j < 4; j++)
#pragma unroll
            for (int r = 0; r < 4; r++) {
                const int t = t0 + wr + i * 16 + q * 4 + r;
                const int s = s0 + wc + j * 16 + l15;
                u16 o = (t < s) ? (u16)0xFF7F : f2b(acc[i][j][r] * 0.03125f);
                S[((size_t)(b * T_ + t)) * T_ + s] = o;
            }
}

// ---------------- K2b: per-column (m, 1/z) over t >= s ----------------
__global__ __launch_bounds__(256) void k2b_stats(u16* __restrict__ S)
{
    __shared__ u16 St[64 * 64];
    __shared__ float sm[4][64], sz[4][64];
    const int tid = threadIdx.x;
    const int lane = tid & 63, w = tid >> 6;
    const int b = blockIdx.y;
    const int s0 = blockIdx.x * 64;
    const u16* Sb = S + (size_t)b * T_ * T_;
    float m = -3e38f, z = 0.f;
    for (int t0 = s0; t0 < T_; t0 += 64) {
        __syncthreads();
#pragma unroll
        for (int u = 0; u < 2; u++) {
            const int c = tid * 2 + u;
            const int row = c >> 3, off = c & 7;
            *(uint4*)&St[row * 64 + off * 8] =
                *(const uint4*)(Sb + (size_t)(t0 + row) * T_ + s0 + off * 8);
        }
        __syncthreads();
#pragma unroll
        for (int i = 0; i < 16; i++) {
            const float v = b2f(St[(w * 16 + i) * 64 + lane]);
            if (v > m) { z = z * __expf(m - v) + 1.f; m = v; }
            else z += __expf(v - m);
        }
    }
    sm[w][lane] = m; sz[w][lane] = z;
    __syncthreads();
    if (tid < 64) {
        float mm = sm[0][tid];
#pragma unroll
        for (int rr = 1; rr < 4; rr++) mm = fmaxf(mm, sm[rr][tid]);
        float zz = 0.f;
#pragma unroll
        for (int rr = 0; rr < 4; rr++) zz += sz[rr][tid] * __expf(sm[rr][tid] - mm);
        *mr_ptr(S, 0, b, s0 + tid) = mm;
        *mr_ptr(S, 1, b, s0 + tid) = 1.0f / zz;
    }
}

// ---------------- K3: P = exp(S - m_s) * r_s  (in place, causal-restricted) ----------------
__global__ __launch_bounds__(256) void k3_pnorm(u16* __restrict__ S)
{
    const int row = blockIdx.x;          // b*T + t
    const int b = row >> 11;
    const int t = row & (T_ - 1);
    const int sEnd = ((t >> 7) + 1) << 7;
    const int s0 = threadIdx.x * 8;
    if (s0 >= sEnd) return;
    u16* Sp = S + (size_t)row * T_ + s0;
    const float* mp = mr_ptr(S, 0, b, s0);
    const float* rp = mr_ptr(S, 1, b, s0);
    float mv[8], rv[8];
    *(float4*)&mv[0] = *(const float4*)mp;
    *(float4*)&mv[4] = *((const float4*)mp + 1);
    *(float4*)&rv[0] = *(const float4*)rp;
    *(float4*)&rv[4] = *((const float4*)rp + 1);
    ushort4 v0 = *(ushort4*)Sp;
    ushort4 v1 = *(ushort4*)(Sp + 4);
    u16 vv[8] = { v0.x, v0.y, v0.z, v0.w, v1.x, v1.y, v1.z, v1.w };
    u16 ov[8];
#pragma unroll
    for (int i = 0; i < 8; i++) {
        const int s = s0 + i;
        float p = 0.f;
        if (s <= t) p = __expf(b2f(vv[i]) - mv[i]) * rv[i];
        ov[i] = f2b(p);
    }
    *(ushort4*)Sp       = make_ushort4(ov[0], ov[1], ov[2], ov[3]);
    *(ushort4*)(Sp + 4) = make_ushort4(ov[4], ov[5], ov[6], ov[7]);
}

// ---------------- K4: out = P @ x  (MFMA, B via LDS fp32 transpose stage) ----------------
__global__ __launch_bounds__(256) void k4_out(const u16* __restrict__ P,
                                              const float* __restrict__ x,
                                              float* __restrict__ out)
{
    __shared__ u16 As[128 * PIT];        // P tile: 128 t x 32 s
    __shared__ u16 Bs[128 * PIT];        // xT tile: 128 d x 32 s
    __shared__ float Xs[32 * 132];       // x tile: 32 s x 128 d (fp32, pitch 132)
    const int tid = threadIdx.x;
    const int lane = tid & 63, wid = tid >> 6;
    const int wr = (wid >> 1) * 64, wc = (wid & 1) * 64;
    const int l15 = lane & 15, q = lane >> 4;
    const int it = (T_ / 128 - 1) - blockIdx.y;   // heavy tiles first
    const int t0 = it * 128;
    const int d0 = blockIdx.x * 128;
    const int b = blockIdx.z;
    const u16* Pb = P + (size_t)b * T_ * T_;
    const float* xb = x + (size_t)b * T_ * D_;
    const int gn = tid & 127;            // pack column (d)
    const int kh0 = (tid >> 7) * 2;      // 0 or 2

    floatx4 acc[4][4];
#pragma unroll
    for (int i = 0; i < 4; i++)
#pragma unroll
        for (int j = 0; j < 4; j++) acc[i][j] = (floatx4){0.f, 0.f, 0.f, 0.f};

    const int kend = t0 + 128;
    for (int k0 = 0; k0 < kend; k0 += 32) {
        __syncthreads();
        // A: P rows, pure 16B copies
#pragma unroll
        for (int u = 0; u < 2; u++) {
            const int c = tid * 2 + u;
            const int row = c >> 2, off = c & 3;
            *(uint4*)&As[row * PIT + off * 8] =
                *(const uint4*)(Pb + (size_t)(t0 + row) * T_ + k0 + off * 8);
        }
        // Xs: x[k0..+32][d0..+128] fp32, coalesced float4
#pragma unroll
        for (int u = 0; u < 4; u++) {
            const int c = tid + 256 * u;
            const int row = c >> 5, c4 = c & 31;
            float4 v = *(const float4*)(xb + (size_t)(k0 + row) * D_ + d0 + c4 * 4);
            *(float4*)&Xs[row * 132 + c4 * 4] = v;
        }
        __syncthreads();
        // pack: column gn of Xs -> bf16 short8 -> b128 into Bs[d][k]
#pragma unroll
        for (int u = 0; u < 2; u++) {
            const int kh = kh0 + u;
            float f[8];
#pragma unroll
            for (int j = 0; j < 8; j++) f[j] = Xs[(kh * 8 + j) * 132 + gn];
            uint4 pk = make_uint4(pkbf(f[0], f[1]), pkbf(f[2], f[3]),
                                  pkbf(f[4], f[5]), pkbf(f[6], f[7]));
            *(uint4*)&Bs[gn * PIT + kh * 8] = pk;
        }
        __syncthreads();
        short8 a[4], b2[4];
#pragma unroll
        for (int i = 0; i < 4; i++) a[i] = *(const short8*)&As[(wr + i * 16 + l15) * PIT + q * 8];
#pragma unroll
        for (int j = 0; j < 4; j++) b2[j] = *(const short8*)&Bs[(wc + j * 16 + l15) * PIT + q * 8];
#pragma unroll
        for (int i = 0; i < 4; i++)
#pragma unroll
            for (int j = 0; j < 4; j++)
                acc[i][j] = __builtin_amdgcn_mfma_f32_16x16x32_bf16(a[i], b2[j], acc[i][j], 0, 0, 0);
    }
#pragma unroll
    for (int i = 0; i < 4; i++)
#pragma unroll
        for (int j = 0; j < 4; j++)
#pragma unroll
            for (int r = 0; r < 4; r++) {
                const int gt = t0 + wr + i * 16 + q * 4 + r;
                const int gd = d0 + wc + j * 16 + l15;
                out[(size_t)(b * T_ + gt) * D_ + gd] = acc[i][j][r];
            }
}

extern "C" void kernel_launch(void* const* d_in, const int* in_sizes, int n_in,
                              void* d_out, int out_size, void* d_ws, size_t ws_size,
                              hipStream_t stream)
{
    const float* x    = (const float*)d_in[0];
    const float* W    = (const float*)d_in[1];
    const float* bias = (const float*)d_in[2];
    float* outf = (float*)d_out;
    u16*   y    = (u16*)d_out;                  // bf16, first 32 MiB of d_out
    u16*   WT   = y + ((size_t)1 << 24);        // 32MiB..34MiB of d_out (dead before k4)
    u16*   S    = (u16*)d_ws;                   // 64 MiB (m/r stashed in dead zone)

    dim3 g0(D_ / 64, E_ / 64);            // (16,16)
    k0_wt<<<g0, 256, 0, stream>>>(W, WT);

    dim3 g1(E_ / 128, (B_ * T_) / 128);   // (8, 128)
    k1_proj<<<g1, 256, 0, stream>>>(x, WT, bias, y);

    dim3 g2(136, B_);
    k2_score<<<g2, 256, 0, stream>>>(y, S);

    dim3 g2b(T_ / 64, B_);                // (32, 8)
    k2b_stats<<<g2b, 256, 0, stream>>>(S);

    dim3 g3(B_ * T_);
    k3_pnorm<<<g3, 256, 0, stream>>>(S);

    dim3 g4(D_ / 128, T_ / 128, B_);      // (8, 16, 8)
    k4_out<<<g4, 256, 0, stream>>>(S, x, outf);
}

// Round 6
// 423.040 us; speedup vs baseline: 1.1044x; 1.1044x over previous
//
#include <hip/hip_runtime.h>
#include <hip/hip_bf16.h>

// B=8, T=2048, D=1024, E=1024
//   k0 : WT = bf16(W^T)                 -> d_out[32MiB..34MiB] (dead before k4)
//   k00: xT = bf16(x^T) [B][D][T]       -> d_ws[64MiB..96MiB]  (only if ws >= 96MiB)
//   k1 : y = bf16(x@W + b)              -> d_out[0:32MiB]   (MFMA)
//   k2 : S[b,t,s] = bf16(y_t.y_s/32)    -> d_ws, lower-triangle tiles
//        (m97-style: global_load_lds width-16, XOR-swizzled unpadded LDS)
//   k2b: col stats m_s, r_s=1/z_s       -> stashed in S's dead zone
//   k3 : P = exp(S-m_s)*r_s in place    (causal-restricted)
//   k4 : out = P @ x  fp32  — fast path: m97-style from P and xT;
//        fallback: round-4 scalar-gather version.
//
// MFMA 16x16x32 bf16 frag layouts (HW-verified):
//   A: lane holds A[m=lane&15][k=q*8+j]; B: B[k=q*8+j][n=lane&15]
//   C/D: lane,reg r -> D[row=q*4+r][col=lane&15]
// Swizzled LDS tile (128 rows x 64 shorts, no pad): 16B chunk slot c of row r
// holds logical chunk c ^ (r&7). Both global_load_lds lane-contiguous writes
// and b128 frag reads then hit every bank exactly 8 dwords = minimum.

#define B_ 8
#define T_ 2048
#define D_ 1024
#define E_ 1024
#define PIT 56

typedef unsigned short u16;
typedef __attribute__((ext_vector_type(8))) short short8;
typedef __attribute__((ext_vector_type(4))) float floatx4;

__device__ __forceinline__ float b2f(u16 u) {
    unsigned v = ((unsigned)u) << 16;
    float f; __builtin_memcpy(&f, &v, 4); return f;
}
__device__ __forceinline__ u16 f2b(float f) {
    unsigned v; __builtin_memcpy(&v, &f, 4);
    v = (v + 0x7FFFu + ((v >> 16) & 1u)) >> 16;   // RNE
    return (u16)v;
}
__device__ __forceinline__ unsigned pkbf(float a, float b) {
    __hip_bfloat162 h = __float22bfloat162_rn(make_float2(a, b));
    unsigned u; __builtin_memcpy(&u, &h, 4); return u;
}

// async 16B global -> LDS (lds dest = wave-uniform base + lane*16)
__device__ __forceinline__ void gl2lds16(const u16* gp, u16* lp) {
    __builtin_amdgcn_global_load_lds(
        (const __attribute__((address_space(1))) void*)(gp),
        (__attribute__((address_space(3))) void*)(lp), 16, 0, 0);
}

// stage a 128-row x 64-short bf16 tile (row stride srow shorts, col offset kc)
// into swizzled LDS; wave wid covers rows [wid*32, wid*32+32).
__device__ __forceinline__ void stage128x64(const u16* src, size_t srow, int kc,
                                            u16* lds, int wid, int lane)
{
    const int rl = lane >> 3, c = lane & 7;
    const int g = ((c ^ rl) << 3);
#pragma unroll
    for (int cc = 0; cc < 4; cc++) {
        const int r = wid * 32 + cc * 8;
        gl2lds16(src + (size_t)(r + rl) * srow + kc + g, &lds[r * 64]);
    }
}

// m/r stash inside S's strictly-upper dead zone (batch 0, rows 0..63, cols 1024+).
__device__ __forceinline__ float* mr_ptr(u16* S, int which, int b, int s) {
    const int row = which * 32 + b * 4 + (s >> 9);
    return (float*)(S + (size_t)row * T_ + 1024 + (s & 511) * 2);
}

// ---------------- K0: WT[n][k] = bf16(W[k][n]) ----------------
__global__ __launch_bounds__(256) void k0_wt(const float* __restrict__ W,
                                             u16* __restrict__ WT)
{
    __shared__ float Ws[64 * 68];
    const int tid = threadIdx.x;
    const int k0 = blockIdx.x * 64, n0 = blockIdx.y * 64;
#pragma unroll
    for (int u = 0; u < 4; u++) {
        const int c = tid + 256 * u;
        const int row = c >> 4, c4 = c & 15;
        float4 v = *(const float4*)(W + (size_t)(k0 + row) * E_ + n0 + c4 * 4);
        *(float4*)&Ws[row * 68 + c4 * 4] = v;
    }
    __syncthreads();
#pragma unroll
    for (int u = 0; u < 2; u++) {
        const int c = tid + 256 * u;
        const int n = c >> 3, kc = c & 7;
        unsigned pk[4];
#pragma unroll
        for (int j = 0; j < 4; j++)
            pk[j] = pkbf(Ws[(kc * 8 + 2 * j) * 68 + n], Ws[(kc * 8 + 2 * j + 1) * 68 + n]);
        *(uint4*)(WT + (size_t)(n0 + n) * D_ + k0 + kc * 8) = make_uint4(pk[0], pk[1], pk[2], pk[3]);
    }
}

// ---------------- K00: xT[b][d][t] = bf16(x[b][t][d]) ----------------
__global__ __launch_bounds__(256) void k00_xt(const float* __restrict__ x,
                                              u16* __restrict__ XT)
{
    __shared__ float Xs[64 * 68];
    const int tid = threadIdx.x;
    const int s0 = blockIdx.x * 64, d0 = blockIdx.y * 64, b = blockIdx.z;
    const float* xb = x + (size_t)b * T_ * D_;
#pragma unroll
    for (int u = 0; u < 4; u++) {
        const int c = tid + 256 * u;
        const int row = c >> 4, c4 = c & 15;
        float4 v = *(const float4*)(xb + (size_t)(s0 + row) * D_ + d0 + c4 * 4);
        *(float4*)&Xs[row * 68 + c4 * 4] = v;
    }
    __syncthreads();
#pragma unroll
    for (int u = 0; u < 2; u++) {
        const int c = tid + 256 * u;
        const int d = c >> 3, sc = c & 7;
        unsigned pk[4];
#pragma unroll
        for (int j = 0; j < 4; j++)
            pk[j] = pkbf(Xs[(sc * 8 + 2 * j) * 68 + d], Xs[(sc * 8 + 2 * j + 1) * 68 + d]);
        *(uint4*)(XT + ((size_t)(b * D_ + d0 + d)) * T_ + s0 + sc * 8) =
            make_uint4(pk[0], pk[1], pk[2], pk[3]);
    }
}

// ---------------- K1: y = bf16(x @ W + b), MFMA ----------------
__global__ __launch_bounds__(256) void k1_proj(const float* __restrict__ x,
                                               const u16* __restrict__ WT,
                                               const float* __restrict__ bias,
                                               u16* __restrict__ y)
{
    __shared__ u16 As[128 * PIT];
    __shared__ u16 Bs[128 * PIT];
    const int tid = threadIdx.x;
    const int lane = tid & 63, wid = tid >> 6;
    const int wr = (wid >> 1) * 64, wc = (wid & 1) * 64;
    const int l15 = lane & 15, q = lane >> 4;
    const int m0 = blockIdx.y * 128, n0 = blockIdx.x * 128;

    floatx4 acc[4][4];
#pragma unroll
    for (int i = 0; i < 4; i++)
#pragma unroll
        for (int j = 0; j < 4; j++) acc[i][j] = (floatx4){0.f, 0.f, 0.f, 0.f};

    for (int k0 = 0; k0 < D_; k0 += 32) {
        __syncthreads();
#pragma unroll
        for (int u = 0; u < 4; u++) {
            const int c = tid * 4 + u;
            const int row = c >> 3, c4 = c & 7;
            float4 v = *(const float4*)(x + (size_t)(m0 + row) * D_ + k0 + c4 * 4);
            *(uint2*)&As[row * PIT + c4 * 4] = make_uint2(pkbf(v.x, v.y), pkbf(v.z, v.w));
        }
#pragma unroll
        for (int u = 0; u < 2; u++) {
            const int c = tid * 2 + u;
            const int row = c >> 2, off = c & 3;
            *(uint4*)&Bs[row * PIT + off * 8] =
                *(const uint4*)(WT + (size_t)(n0 + row) * D_ + k0 + off * 8);
        }
        __syncthreads();
        short8 a[4], b2[4];
#pragma unroll
        for (int i = 0; i < 4; i++) a[i] = *(const short8*)&As[(wr + i * 16 + l15) * PIT + q * 8];
#pragma unroll
        for (int j = 0; j < 4; j++) b2[j] = *(const short8*)&Bs[(wc + j * 16 + l15) * PIT + q * 8];
#pragma unroll
        for (int i = 0; i < 4; i++)
#pragma unroll
            for (int j = 0; j < 4; j++)
                acc[i][j] = __builtin_amdgcn_mfma_f32_16x16x32_bf16(a[i], b2[j], acc[i][j], 0, 0, 0);
    }
    float bv[4];
#pragma unroll
    for (int j = 0; j < 4; j++) bv[j] = bias[n0 + wc + j * 16 + l15];
#pragma unroll
    for (int i = 0; i < 4; i++)
#pragma unroll
        for (int j = 0; j < 4; j++)
#pragma unroll
            for (int r = 0; r < 4; r++) {
                const int gm = m0 + wr + i * 16 + q * 4 + r;
                const int gn = n0 + wc + j * 16 + l15;
                y[(size_t)gm * E_ + gn] = f2b(acc[i][j][r] + bv[j]);
            }
}

// ---------------- K2: S tiles, m97-style staging, BK=64 ----------------
__global__ __launch_bounds__(256) void k2_score(const u16* __restrict__ y,
                                                u16* __restrict__ S)
{
    __shared__ u16 As[128 * 64];
    __shared__ u16 Bs[128 * 64];
    const int tid = threadIdx.x;
    const int lane = tid & 63, wid = tid >> 6;
    const int wr = (wid >> 1) * 64, wc = (wid & 1) * 64;
    const int l15 = lane & 15, q = lane >> 4;
    const int sw = l15 & 7;
    int idx = blockIdx.x, it = 0, base = 0;
    while (base + it + 1 <= idx) { base += it + 1; it++; }
    const int js = idx - base;
    const int t0 = it * 128, s0 = js * 128;
    const int b = blockIdx.y;
    const u16* yb = y + (size_t)b * T_ * E_;

    floatx4 acc[4][4];
#pragma unroll
    for (int i = 0; i < 4; i++)
#pragma unroll
        for (int j = 0; j < 4; j++) acc[i][j] = (floatx4){0.f, 0.f, 0.f, 0.f};

    for (int k0 = 0; k0 < E_; k0 += 64) {
        __syncthreads();
        stage128x64(yb + (size_t)t0 * E_, E_, k0, As, wid, lane);
        stage128x64(yb + (size_t)s0 * E_, E_, k0, Bs, wid, lane);
        __syncthreads();
#pragma unroll
        for (int h = 0; h < 2; h++) {
            short8 a[4], b2[4];
#pragma unroll
            for (int i = 0; i < 4; i++)
                a[i] = *(const short8*)&As[(wr + i * 16 + l15) * 64 + (((h * 4 + q) ^ sw) << 3)];
#pragma unroll
            for (int j = 0; j < 4; j++)
                b2[j] = *(const short8*)&Bs[(wc + j * 16 + l15) * 64 + (((h * 4 + q) ^ sw) << 3)];
#pragma unroll
            for (int i = 0; i < 4; i++)
#pragma unroll
                for (int j = 0; j < 4; j++)
                    acc[i][j] = __builtin_amdgcn_mfma_f32_16x16x32_bf16(a[i], b2[j], acc[i][j], 0, 0, 0);
        }
    }
#pragma unroll
    for (int i = 0; i < 4; i++)
#pragma unroll
        for (int j = 0; j < 4; j++)
#pragma unroll
            for (int r = 0; r < 4; r++) {
                const int t = t0 + wr + i * 16 + q * 4 + r;
                const int s = s0 + wc + j * 16 + l15;
                u16 o = (t < s) ? (u16)0xFF7F : f2b(acc[i][j][r] * 0.03125f);
                S[((size_t)(b * T_ + t)) * T_ + s] = o;
            }
}

// ---------------- K2b: per-column (m, 1/z) over t >= s ----------------
__global__ __launch_bounds__(256) void k2b_stats(u16* __restrict__ S)
{
    __shared__ u16 St[64 * 64];
    __shared__ float sm[4][64], sz[4][64];
    const int tid = threadIdx.x;
    const int lane = tid & 63, w = tid >> 6;
    const int b = blockIdx.y;
    const int s0 = blockIdx.x * 64;
    const u16* Sb = S + (size_t)b * T_ * T_;
    float m = -3e38f, z = 0.f;
    for (int t0 = s0; t0 < T_; t0 += 64) {
        __syncthreads();
#pragma unroll
        for (int u = 0; u < 2; u++) {
            const int c = tid * 2 + u;
            const int row = c >> 3, off = c & 7;
            *(uint4*)&St[row * 64 + off * 8] =
                *(const uint4*)(Sb + (size_t)(t0 + row) * T_ + s0 + off * 8);
        }
        __syncthreads();
#pragma unroll
        for (int i = 0; i < 16; i++) {
            const float v = b2f(St[(w * 16 + i) * 64 + lane]);
            if (v > m) { z = z * __expf(m - v) + 1.f; m = v; }
            else z += __expf(v - m);
        }
    }
    sm[w][lane] = m; sz[w][lane] = z;
    __syncthreads();
    if (tid < 64) {
        float mm = sm[0][tid];
#pragma unroll
        for (int rr = 1; rr < 4; rr++) mm = fmaxf(mm, sm[rr][tid]);
        float zz = 0.f;
#pragma unroll
        for (int rr = 0; rr < 4; rr++) zz += sz[rr][tid] * __expf(sm[rr][tid] - mm);
        *mr_ptr(S, 0, b, s0 + tid) = mm;
        *mr_ptr(S, 1, b, s0 + tid) = 1.0f / zz;
    }
}

// ---------------- K3: P = exp(S - m_s) * r_s  (in place, causal-restricted) ----------------
__global__ __launch_bounds__(256) void k3_pnorm(u16* __restrict__ S)
{
    const int row = blockIdx.x;          // b*T + t
    const int b = row >> 11;
    const int t = row & (T_ - 1);
    const int sEnd = ((t >> 7) + 1) << 7;
    const int s0 = threadIdx.x * 8;
    if (s0 >= sEnd) return;
    u16* Sp = S + (size_t)row * T_ + s0;
    const float* mp = mr_ptr(S, 0, b, s0);
    const float* rp = mr_ptr(S, 1, b, s0);
    float mv[8], rv[8];
    *(float4*)&mv[0] = *(const float4*)mp;
    *(float4*)&mv[4] = *((const float4*)mp + 1);
    *(float4*)&rv[0] = *(const float4*)rp;
    *(float4*)&rv[4] = *((const float4*)rp + 1);
    ushort4 v0 = *(ushort4*)Sp;
    ushort4 v1 = *(ushort4*)(Sp + 4);
    u16 vv[8] = { v0.x, v0.y, v0.z, v0.w, v1.x, v1.y, v1.z, v1.w };
    u16 ov[8];
#pragma unroll
    for (int i = 0; i < 8; i++) {
        const int s = s0 + i;
        float p = 0.f;
        if (s <= t) p = __expf(b2f(vv[i]) - mv[i]) * rv[i];
        ov[i] = f2b(p);
    }
    *(ushort4*)Sp       = make_ushort4(ov[0], ov[1], ov[2], ov[3]);
    *(ushort4*)(Sp + 4) = make_ushort4(ov[4], ov[5], ov[6], ov[7]);
}

// ---------------- K4 fast: out = P @ xT^T, m97-style, BK=64 ----------------
__global__ __launch_bounds__(256) void k4_fast(const u16* __restrict__ P,
                                               const u16* __restrict__ XT,
                                               float* __restrict__ out)
{
    __shared__ u16 As[128 * 64];
    __shared__ u16 Bs[128 * 64];
    const int tid = threadIdx.x;
    const int lane = tid & 63, wid = tid >> 6;
    const int wr = (wid >> 1) * 64, wc = (wid & 1) * 64;
    const int l15 = lane & 15, q = lane >> 4;
    const int sw = l15 & 7;
    const int it = (T_ / 128 - 1) - blockIdx.y;   // heavy tiles first
    const int t0 = it * 128;
    const int d0 = blockIdx.x * 128;
    const int b = blockIdx.z;
    const u16* Pb = P + (size_t)b * T_ * T_ + (size_t)t0 * T_;
    const u16* Xb = XT + (size_t)(b * D_ + d0) * T_;

    floatx4 acc[4][4];
#pragma unroll
    for (int i = 0; i < 4; i++)
#pragma unroll
        for (int j = 0; j < 4; j++) acc[i][j] = (floatx4){0.f, 0.f, 0.f, 0.f};

    const int kend = t0 + 128;
    for (int k0 = 0; k0 < kend; k0 += 64) {
        __syncthreads();
        stage128x64(Pb, T_, k0, As, wid, lane);
        stage128x64(Xb, T_, k0, Bs, wid, lane);
        __syncthreads();
#pragma unroll
        for (int h = 0; h < 2; h++) {
            short8 a[4], b2[4];
#pragma unroll
            for (int i = 0; i < 4; i++)
                a[i] = *(const short8*)&As[(wr + i * 16 + l15) * 64 + (((h * 4 + q) ^ sw) << 3)];
#pragma unroll
            for (int j = 0; j < 4; j++)
                b2[j] = *(const short8*)&Bs[(wc + j * 16 + l15) * 64 + (((h * 4 + q) ^ sw) << 3)];
#pragma unroll
            for (int i = 0; i < 4; i++)
#pragma unroll
                for (int j = 0; j < 4; j++)
                    acc[i][j] = __builtin_amdgcn_mfma_f32_16x16x32_bf16(a[i], b2[j], acc[i][j], 0, 0, 0);
        }
    }
#pragma unroll
    for (int i = 0; i < 4; i++)
#pragma unroll
        for (int j = 0; j < 4; j++)
#pragma unroll
            for (int r = 0; r < 4; r++) {
                const int gt = t0 + wr + i * 16 + q * 4 + r;
                const int gd = d0 + wc + j * 16 + l15;
                out[(size_t)(b * T_ + gt) * D_ + gd] = acc[i][j][r];
            }
}

// ---------------- K4 fallback (round-4): scalar-gather B-stage ----------------
__global__ __launch_bounds__(256) void k4_fb(const u16* __restrict__ P,
                                             const float* __restrict__ x,
                                             float* __restrict__ out)
{
    __shared__ u16 As[128 * PIT];
    __shared__ u16 Bs[128 * PIT];
    const int tid = threadIdx.x;
    const int lane = tid & 63, wid = tid >> 6;
    const int wr = (wid >> 1) * 64, wc = (wid & 1) * 64;
    const int l15 = lane & 15, q = lane >> 4;
    const int it = (T_ / 128 - 1) - blockIdx.y;
    const int t0 = it * 128;
    const int d0 = blockIdx.x * 128;
    const int b = blockIdx.z;
    const u16* Pb = P + (size_t)b * T_ * T_;
    const float* xb = x + (size_t)b * T_ * D_;
    const int gn = tid & 127;
    const int kh0 = (tid >> 7) * 2;

    floatx4 acc[4][4];
#pragma unroll
    for (int i = 0; i < 4; i++)
#pragma unroll
        for (int j = 0; j < 4; j++) acc[i][j] = (floatx4){0.f, 0.f, 0.f, 0.f};

    const int kend = t0 + 128;
    for (int k0 = 0; k0 < kend; k0 += 32) {
        __syncthreads();
#pragma unroll
        for (int u = 0; u < 2; u++) {
            const int c = tid * 2 + u;
            const int row = c >> 2, off = c & 3;
            *(uint4*)&As[row * PIT + off * 8] =
                *(const uint4*)(Pb + (size_t)(t0 + row) * T_ + k0 + off * 8);
        }
#pragma unroll
        for (int u = 0; u < 2; u++) {
            const int kh = kh0 + u;
            float f[8];
#pragma unroll
            for (int j = 0; j < 8; j++)
                f[j] = xb[(size_t)(k0 + kh * 8 + j) * D_ + d0 + gn];
            uint4 pk = make_uint4(pkbf(f[0], f[1]), pkbf(f[2], f[3]),
                                  pkbf(f[4], f[5]), pkbf(f[6], f[7]));
            *(uint4*)&Bs[gn * PIT + kh * 8] = pk;
        }
        __syncthreads();
        short8 a[4], b2[4];
#pragma unroll
        for (int i = 0; i < 4; i++) a[i] = *(const short8*)&As[(wr + i * 16 + l15) * PIT + q * 8];
#pragma unroll
        for (int j = 0; j < 4; j++) b2[j] = *(const short8*)&Bs[(wc + j * 16 + l15) * PIT + q * 8];
#pragma unroll
        for (int i = 0; i < 4; i++)
#pragma unroll
            for (int j = 0; j < 4; j++)
                acc[i][j] = __builtin_amdgcn_mfma_f32_16x16x32_bf16(a[i], b2[j], acc[i][j], 0, 0, 0);
    }
#pragma unroll
    for (int i = 0; i < 4; i++)
#pragma unroll
        for (int j = 0; j < 4; j++)
#pragma unroll
            for (int r = 0; r < 4; r++) {
                const int gt = t0 + wr + i * 16 + q * 4 + r;
                const int gd = d0 + wc + j * 16 + l15;
                out[(size_t)(b * T_ + gt) * D_ + gd] = acc[i][j][r];
            }
}

extern "C" void kernel_launch(void* const* d_in, const int* in_sizes, int n_in,
                              void* d_out, int out_size, void* d_ws, size_t ws_size,
                              hipStream_t stream)
{
    const float* x    = (const float*)d_in[0];
    const float* W    = (const float*)d_in[1];
    const float* bias = (const float*)d_in[2];
    float* outf = (float*)d_out;
    u16*   y    = (u16*)d_out;                  // bf16, first 32 MiB of d_out
    u16*   WT   = y + ((size_t)1 << 24);        // 32MiB..34MiB of d_out (dead before k4)
    u16*   S    = (u16*)d_ws;                   // 64 MiB (m/r stashed in dead zone)
    u16*   XT   = S + ((size_t)1 << 25);        // ws+64MiB..+96MiB (fast path only)
    const bool fast = ws_size >= ((size_t)96 << 20);

    dim3 g0(D_ / 64, E_ / 64);            // (16,16)
    k0_wt<<<g0, 256, 0, stream>>>(W, WT);

    if (fast) {
        dim3 g00(T_ / 64, D_ / 64, B_);   // (32,16,8)
        k00_xt<<<g00, 256, 0, stream>>>(x, XT);
    }

    dim3 g1(E_ / 128, (B_ * T_) / 128);   // (8, 128)
    k1_proj<<<g1, 256, 0, stream>>>(x, WT, bias, y);

    dim3 g2(136, B_);
    k2_score<<<g2, 256, 0, stream>>>(y, S);

    dim3 g2b(T_ / 64, B_);                // (32, 8)
    k2b_stats<<<g2b, 256, 0, stream>>>(S);

    dim3 g3(B_ * T_);
    k3_pnorm<<<g3, 256, 0, stream>>>(S);

    dim3 g4(D_ / 128, T_ / 128, B_);      // (8, 16, 8)
    if (fast) k4_fast<<<g4, 256, 0, stream>>>(S, XT, outf);
    else      k4_fb  <<<g4, 256, 0, stream>>>(S, x, outf);
}